// Round 7
// baseline (251.269 us; speedup 1.0000x reference)
//
#include <hip/hip_runtime.h>
#include <cstdint>

#define NQ 8
#define NKV 16
#define NGRP 4            // kv rows split across 4 block groups
#define KPG (NKV / NGRP)  // 4 kv rows per group
#define NPB 40            // per-block partials: 8x4 products + 8 norms (g0)
#define NSLOT (NGRP * NPB)  // 160 slot-major partial rows
#define NXCD 8

// ---------------- Threefry-2x32 (JAX partitionable path; verified R3) ----
__device__ __forceinline__ unsigned rotl32(unsigned x, int d) {
    return (x << d) | (x >> (32 - d));
}

__device__ __forceinline__ void threefry2x32(unsigned k0, unsigned k1,
                                             unsigned& x0, unsigned& x1) {
    const unsigned ks0 = k0, ks1 = k1, ks2 = k0 ^ k1 ^ 0x1BD11BDAu;
    x0 += ks0; x1 += ks1;
    x0 += x1; x1 = rotl32(x1, 13); x1 ^= x0;
    x0 += x1; x1 = rotl32(x1, 15); x1 ^= x0;
    x0 += x1; x1 = rotl32(x1, 26); x1 ^= x0;
    x0 += x1; x1 = rotl32(x1,  6); x1 ^= x0;
    x0 += ks1; x1 += ks2 + 1u;
    x0 += x1; x1 = rotl32(x1, 17); x1 ^= x0;
    x0 += x1; x1 = rotl32(x1, 29); x1 ^= x0;
    x0 += x1; x1 = rotl32(x1, 16); x1 ^= x0;
    x0 += x1; x1 = rotl32(x1, 24); x1 ^= x0;
    x0 += ks2; x1 += ks0 + 2u;
    x0 += x1; x1 = rotl32(x1, 13); x1 ^= x0;
    x0 += x1; x1 = rotl32(x1, 15); x1 ^= x0;
    x0 += x1; x1 = rotl32(x1, 26); x1 ^= x0;
    x0 += x1; x1 = rotl32(x1,  6); x1 ^= x0;
    x0 += ks0; x1 += ks1 + 3u;
    x0 += x1; x1 = rotl32(x1, 17); x1 ^= x0;
    x0 += x1; x1 = rotl32(x1, 29); x1 ^= x0;
    x0 += x1; x1 = rotl32(x1, 16); x1 ^= x0;
    x0 += x1; x1 = rotl32(x1, 24); x1 ^= x0;
    x0 += ks1; x1 += ks2 + 4u;
    x0 += x1; x1 = rotl32(x1, 13); x1 ^= x0;
    x0 += x1; x1 = rotl32(x1, 15); x1 ^= x0;
    x0 += x1; x1 = rotl32(x1, 26); x1 ^= x0;
    x0 += x1; x1 = rotl32(x1,  6); x1 ^= x0;
    x0 += ks2; x1 += ks0 + 5u;
}

__device__ __forceinline__ int jax_keep_bit(int idx) {
    unsigned x0 = 0u, x1 = (unsigned)idx;
    threefry2x32(0u, 42u, x0, x1);
    unsigned bits = x0 ^ x1;
    unsigned fb = (bits >> 9) | 0x3F800000u;
    float u = __uint_as_float(fb) - 1.0f;
    return u < 0.9f ? 1 : 0;
}

__device__ __forceinline__ float dot4(float4 a, float4 b) {
    return a.x * b.x + a.y * b.y + a.z * b.z + a.w * b.w;
}

// ---------------- Fused kernel -------------------------------------------
// Phase A (all blocks): 4-way kv split, XCD-co-located groups, CONTIGUOUS
// column span per colblock (long sequential DRAM streams, tight L2 q-share).
// Phase B (last block via atomic ticket): reduce slot-major partials,
// softmax + dropout, write out. One dispatch total.
__global__ __launch_bounds__(256, 4) void qk_fused_kernel(
    const float4* __restrict__ qkv, float* __restrict__ partial,
    unsigned* __restrict__ counter, float* __restrict__ out,
    unsigned D4, unsigned ncb, unsigned span)
{
    const int tid  = threadIdx.x;
    const int w    = tid >> 6;
    const int lane = tid & 63;

    unsigned g, cb;
    if ((ncb & (NXCD - 1)) == 0) {
        const unsigned xcd = blockIdx.x & (NXCD - 1);   // same slot under RR
        const unsigned idx = blockIdx.x >> 3;
        g  = idx & (NGRP - 1);                          // g varies fastest
        cb = (idx >> 2) * NXCD + xcd;                   // -> bids differ by 8
    } else {
        g  = blockIdx.x & (NGRP - 1);
        cb = blockIdx.x >> 2;
    }

    const float4* __restrict__ kbase = qkv + (size_t)(NQ + g * KPG) * D4;

    float acc[NQ][KPG];
#pragma unroll
    for (int r = 0; r < NQ; ++r)
#pragma unroll
        for (int j = 0; j < KPG; ++j) acc[r][j] = 0.f;
    float nacc[NQ];
#pragma unroll
    for (int r = 0; r < NQ; ++r) nacc[r] = 0.f;

    // contiguous span [cb*span, (cb+1)*span): block walks 4KB/row/iter
    const unsigned vbeg = cb * span;
    const unsigned vend = (vbeg + span < D4) ? (vbeg + span) : D4;

    for (unsigned v = vbeg + tid; v < vend; v += 256u) {
        float4 kv[KPG];
#pragma unroll
        for (int j = 0; j < KPG; ++j)
            kv[j] = kbase[(size_t)j * D4 + v];
        float4 qv[NQ];
#pragma unroll
        for (int r = 0; r < NQ; ++r)
            qv[r] = qkv[(size_t)r * D4 + v];

        if (g == 0) {
#pragma unroll
            for (int r = 0; r < NQ; ++r)
                nacc[r] += dot4(qv[r], qv[r]);
        }
#pragma unroll
        for (int r = 0; r < NQ; ++r)
#pragma unroll
            for (int j = 0; j < KPG; ++j)
                acc[r][j] += dot4(qv[r], kv[j]);
    }

    // wave shuffle-reduce the 40 partials, cross-wave combine via LDS
    __shared__ float lred[4][NPB];
#pragma unroll
    for (int r = 0; r < NQ; ++r) {
#pragma unroll
        for (int j = 0; j < KPG; ++j) {
            float s = acc[r][j];
#pragma unroll
            for (int off = 32; off >= 1; off >>= 1)
                s += __shfl_xor(s, off, 64);
            if (lane == 0) lred[w][r * KPG + j] = s;
        }
    }
    if (g == 0) {
#pragma unroll
        for (int r = 0; r < NQ; ++r) {
            float s = nacc[r];
#pragma unroll
            for (int off = 32; off >= 1; off >>= 1)
                s += __shfl_xor(s, off, 64);
            if (lane == 0) lred[w][32 + r] = s;
        }
    } else if (lane == 0) {
#pragma unroll
        for (int r = 0; r < NQ; ++r) lred[w][32 + r] = 0.f;
    }
    __syncthreads();
    // slot-major: partial[(g*40+s)*ncb + cb] -> contiguous per-slot reads
    if (tid < NPB) {
        const float s = lred[0][tid] + lred[1][tid] + lred[2][tid] + lred[3][tid];
        partial[(size_t)(g * NPB + tid) * ncb + cb] = s;
    }

    // ---- ticket: last block performs the final reduce + softmax ----
    __threadfence();              // release partial writes (agent scope)
    __syncthreads();
    __shared__ unsigned isLast;
    if (tid == 0)
        isLast = (atomicAdd(counter, 1u) == gridDim.x - 1u) ? 1u : 0u;
    __syncthreads();
    if (!isLast) return;
    __threadfence();              // acquire others' partial writes

    __shared__ float wsum[NSLOT];
    if (tid < NSLOT) {
        float s = 0.f;
        if ((ncb & 3u) == 0u) {
            const float4* p4 =
                (const float4*)(partial + (size_t)tid * ncb);
            for (unsigned i = 0; i < (ncb >> 2); ++i) {
                const float4 v = p4[i];
                s += v.x + v.y + v.z + v.w;
            }
        } else {
            for (unsigned i = 0; i < ncb; ++i)
                s += partial[(size_t)tid * ncb + i];
        }
        wsum[tid] = s;
    }
    __syncthreads();

    if (tid < 128) {
        const int r = tid >> 4, j = tid & 15;
        const float norm = wsum[32 + r];                     // g0 slots 32..39
        const float inv_scale = rsqrtf(norm + 1e-12f);
        const float logit =
            wsum[(j >> 2) * NPB + r * KPG + (j & 3)] * inv_scale;

        float m = logit;
        for (int off = 8; off >= 1; off >>= 1)
            m = fmaxf(m, __shfl_xor(m, off, 64));
        const float e = expf(logit - m);
        float ssum = e;
        for (int off = 8; off >= 1; off >>= 1)
            ssum += __shfl_xor(ssum, off, 64);

        out[tid] = jax_keep_bit(tid) ? (e / ssum / 0.9f) : 0.f;
    }
}

// ---------------- Launch --------------------------------------------------
extern "C" void kernel_launch(void* const* d_in, const int* in_sizes, int n_in,
                              void* d_out, int out_size, void* d_ws, size_t ws_size,
                              hipStream_t stream) {
    const float* qkv = (const float*)d_in[0];
    float* out = (float*)d_out;

    const long long total = (long long)in_sizes[0];
    const unsigned D  = (unsigned)(total / (NQ + NKV));
    const unsigned D4 = D / 4;

    float* wsf = (float*)d_ws;
    const long long cap_floats = (long long)(ws_size / 4);

    unsigned ncb = 256;  // 256 colblocks x 4 groups = 1024 blocks, 1 round
    while ((long long)NSLOT * ncb + 64 > cap_floats && ncb > 1) ncb >>= 1;

    // contiguous span per colblock, multiple of 256 (thread count)
    const unsigned chunks = (D4 + 255u) / 256u;
    const unsigned span = ((chunks + ncb - 1u) / ncb) * 256u;

    float* partial = wsf;                                  // NSLOT * ncb
    unsigned* counter = (unsigned*)(wsf + (size_t)NSLOT * ncb);

    hipMemsetAsync(counter, 0, sizeof(unsigned), stream);
    qk_fused_kernel<<<ncb * NGRP, 256, 0, stream>>>(
        (const float4*)qkv, partial, counter, out, D4, ncb, span);
}

// Round 8
// 146.537 us; speedup vs baseline: 1.7147x; 1.7147x over previous
//
#include <hip/hip_runtime.h>
#include <cstdint>

#define NQ 8
#define NKV 16
#define NGRP 4            // kv rows split across 4 block groups
#define KPG (NKV / NGRP)  // 4 kv rows per group
#define NPB 40            // per-block partials: 8x4 products + 8 norms (g0)
#define NSLOT (NGRP * NPB) // 160 partials per colblock
#define NXCD 8

// ---------------- Threefry-2x32 (JAX partitionable path; verified R3) ----
__device__ __forceinline__ unsigned rotl32(unsigned x, int d) {
    return (x << d) | (x >> (32 - d));
}

__device__ __forceinline__ void threefry2x32(unsigned k0, unsigned k1,
                                             unsigned& x0, unsigned& x1) {
    const unsigned ks0 = k0, ks1 = k1, ks2 = k0 ^ k1 ^ 0x1BD11BDAu;
    x0 += ks0; x1 += ks1;
    x0 += x1; x1 = rotl32(x1, 13); x1 ^= x0;
    x0 += x1; x1 = rotl32(x1, 15); x1 ^= x0;
    x0 += x1; x1 = rotl32(x1, 26); x1 ^= x0;
    x0 += x1; x1 = rotl32(x1,  6); x1 ^= x0;
    x0 += ks1; x1 += ks2 + 1u;
    x0 += x1; x1 = rotl32(x1, 17); x1 ^= x0;
    x0 += x1; x1 = rotl32(x1, 29); x1 ^= x0;
    x0 += x1; x1 = rotl32(x1, 16); x1 ^= x0;
    x0 += x1; x1 = rotl32(x1, 24); x1 ^= x0;
    x0 += ks2; x1 += ks0 + 2u;
    x0 += x1; x1 = rotl32(x1, 13); x1 ^= x0;
    x0 += x1; x1 = rotl32(x1, 15); x1 ^= x0;
    x0 += x1; x1 = rotl32(x1, 26); x1 ^= x0;
    x0 += x1; x1 = rotl32(x1,  6); x1 ^= x0;
    x0 += ks0; x1 += ks1 + 3u;
    x0 += x1; x1 = rotl32(x1, 17); x1 ^= x0;
    x0 += x1; x1 = rotl32(x1, 29); x1 ^= x0;
    x0 += x1; x1 = rotl32(x1, 16); x1 ^= x0;
    x0 += x1; x1 = rotl32(x1, 24); x1 ^= x0;
    x0 += ks1; x1 += ks2 + 4u;
    x0 += x1; x1 = rotl32(x1, 13); x1 ^= x0;
    x0 += x1; x1 = rotl32(x1, 15); x1 ^= x0;
    x0 += x1; x1 = rotl32(x1, 26); x1 ^= x0;
    x0 += x1; x1 = rotl32(x1,  6); x1 ^= x0;
    x0 += ks2; x1 += ks0 + 5u;
}

__device__ __forceinline__ int jax_keep_bit(int idx) {
    unsigned x0 = 0u, x1 = (unsigned)idx;
    threefry2x32(0u, 42u, x0, x1);
    unsigned bits = x0 ^ x1;
    unsigned fb = (bits >> 9) | 0x3F800000u;
    float u = __uint_as_float(fb) - 1.0f;
    return u < 0.9f ? 1 : 0;
}

__device__ __forceinline__ float dot4(float4 a, float4 b) {
    return a.x * b.x + a.y * b.y + a.z * b.z + a.w * b.w;
}

// ---------------- Phase 1: partial dots (R6-proven, clean hot kernel) -----
// 4-way kv split, XCD-co-located groups (bids of one colblock differ by 8 ->
// same XCD under round-robin -> q re-reads hit that XCD's L2), grid-stride.
// NO tail code in this kernel: keeps register allocation load-parallel
// (R7 post-mortem: fused tail cut VGPR to 64 and serialized loads, 3.3x).
__global__ __launch_bounds__(256, 4) void qk_partial_kernel(
    const float4* __restrict__ qkv, float* __restrict__ partial,
    unsigned D4, unsigned ncb)
{
    const int tid = threadIdx.x;
    const int w   = tid >> 6;
    const int lane = tid & 63;

    unsigned g, cb;
    if ((ncb & (NXCD - 1)) == 0) {
        const unsigned xcd = blockIdx.x & (NXCD - 1);
        const unsigned idx = blockIdx.x >> 3;
        g  = idx & (NGRP - 1);
        cb = (idx >> 2) * NXCD + xcd;
    } else {
        g  = blockIdx.x & (NGRP - 1);
        cb = blockIdx.x >> 2;
    }

    const float4* __restrict__ kbase = qkv + (size_t)(NQ + g * KPG) * D4;

    float acc[NQ][KPG];
#pragma unroll
    for (int r = 0; r < NQ; ++r)
#pragma unroll
        for (int j = 0; j < KPG; ++j) acc[r][j] = 0.f;
    float nacc[NQ];
#pragma unroll
    for (int r = 0; r < NQ; ++r) nacc[r] = 0.f;

    const unsigned stride = ncb * 256u;

    for (unsigned v = cb * 256u + tid; v < D4; v += stride) {
        float4 kv[KPG];
#pragma unroll
        for (int j = 0; j < KPG; ++j)
            kv[j] = kbase[(size_t)j * D4 + v];
        float4 qv[NQ];
#pragma unroll
        for (int r = 0; r < NQ; ++r)
            qv[r] = qkv[(size_t)r * D4 + v];

        if (g == 0) {
#pragma unroll
            for (int r = 0; r < NQ; ++r)
                nacc[r] += dot4(qv[r], qv[r]);
        }
#pragma unroll
        for (int r = 0; r < NQ; ++r)
#pragma unroll
            for (int j = 0; j < KPG; ++j)
                acc[r][j] += dot4(qv[r], kv[j]);
    }

    // wave shuffle-reduce the 40 partials, cross-wave combine via LDS
    __shared__ float lred[4][NPB];
#pragma unroll
    for (int r = 0; r < NQ; ++r) {
#pragma unroll
        for (int j = 0; j < KPG; ++j) {
            float s = acc[r][j];
#pragma unroll
            for (int off = 32; off >= 1; off >>= 1)
                s += __shfl_xor(s, off, 64);
            if (lane == 0) lred[w][r * KPG + j] = s;
        }
    }
    if (g == 0) {
#pragma unroll
        for (int r = 0; r < NQ; ++r) {
            float s = nacc[r];
#pragma unroll
            for (int off = 32; off >= 1; off >>= 1)
                s += __shfl_xor(s, off, 64);
            if (lane == 0) lred[w][32 + r] = s;
        }
    } else if (lane == 0) {
#pragma unroll
        for (int r = 0; r < NQ; ++r) lred[w][32 + r] = 0.f;
    }
    __syncthreads();
    // layout: partial[cb*160 + g*40 + slot] -> finalize reads coalesced
    if (tid < NPB) {
        const float s = lred[0][tid] + lred[1][tid] + lred[2][tid] + lred[3][tid];
        partial[(size_t)cb * NSLOT + g * NPB + tid] = s;
    }
}

// ---------------- Phase 2+3 fused: reduce + softmax + dropout -------------
// One block. Threads 0..159 each own one slot; per-cb reads are contiguous
// (partial[cb*160 + tid]). Then 16-lane-group softmax + threefry mask.
__global__ __launch_bounds__(256) void finalize_kernel(
    const float* __restrict__ partial, float* __restrict__ out, int ncb)
{
    const int tid = threadIdx.x;

    __shared__ float wsum[NSLOT];
    if (tid < NSLOT) {
        float s = 0.f;
        for (int cb = 0; cb < ncb; ++cb)
            s += partial[(size_t)cb * NSLOT + tid];
        wsum[tid] = s;
    }
    __syncthreads();

    if (tid < 128) {
        const int r = tid >> 4, j = tid & 15;
        const float norm = wsum[32 + r];  // g0 norm slots 32..39
        const float inv_scale = rsqrtf(norm + 1e-12f);
        const float logit =
            wsum[(j >> 2) * NPB + r * KPG + (j & 3)] * inv_scale;

        float m = logit;
        for (int off = 8; off >= 1; off >>= 1)
            m = fmaxf(m, __shfl_xor(m, off, 64));
        const float e = expf(logit - m);
        float ssum = e;
        for (int off = 8; off >= 1; off >>= 1)
            ssum += __shfl_xor(ssum, off, 64);

        out[tid] = jax_keep_bit(tid) ? (e / ssum / 0.9f) : 0.f;
    }
}

// ---------------- Launch --------------------------------------------------
extern "C" void kernel_launch(void* const* d_in, const int* in_sizes, int n_in,
                              void* d_out, int out_size, void* d_ws, size_t ws_size,
                              hipStream_t stream) {
    const float* qkv = (const float*)d_in[0];
    float* out = (float*)d_out;

    const long long total = (long long)in_sizes[0];
    const unsigned D  = (unsigned)(total / (NQ + NKV));
    const unsigned D4 = D / 4;

    float* wsf = (float*)d_ws;
    const long long cap_floats = (long long)(ws_size / 4);

    unsigned ncb = 256;  // 256 colblocks x 4 groups = 1024 blocks, 1 round
    while ((long long)NSLOT * ncb > cap_floats && ncb > 1) ncb >>= 1;

    float* partial = wsf;  // NSLOT * ncb floats

    qk_partial_kernel<<<ncb * NGRP, 256, 0, stream>>>(
        (const float4*)qkv, partial, D4, ncb);
    finalize_kernel<<<1, 256, 0, stream>>>(partial, out, (int)ncb);
}

// Round 9
// 113.491 us; speedup vs baseline: 2.2140x; 1.2912x over previous
//
#include <hip/hip_runtime.h>
#include <cstdint>

#define NQ 8
#define NKV 16
#define NGRP 4             // kv rows split across 4 block groups
#define KPG (NKV / NGRP)   // 4 kv rows per group
#define NPB 40             // per-group partial slots: 8x4 products + 8 norms
#define NSLOT (NGRP * NPB) // 160 slots
#define NXCD 8

// ---------------- Threefry-2x32 (JAX partitionable path; verified R3) ----
__device__ __forceinline__ unsigned rotl32(unsigned x, int d) {
    return (x << d) | (x >> (32 - d));
}

__device__ __forceinline__ void threefry2x32(unsigned k0, unsigned k1,
                                             unsigned& x0, unsigned& x1) {
    const unsigned ks0 = k0, ks1 = k1, ks2 = k0 ^ k1 ^ 0x1BD11BDAu;
    x0 += ks0; x1 += ks1;
    x0 += x1; x1 = rotl32(x1, 13); x1 ^= x0;
    x0 += x1; x1 = rotl32(x1, 15); x1 ^= x0;
    x0 += x1; x1 = rotl32(x1, 26); x1 ^= x0;
    x0 += x1; x1 = rotl32(x1,  6); x1 ^= x0;
    x0 += ks1; x1 += ks2 + 1u;
    x0 += x1; x1 = rotl32(x1, 17); x1 ^= x0;
    x0 += x1; x1 = rotl32(x1, 29); x1 ^= x0;
    x0 += x1; x1 = rotl32(x1, 16); x1 ^= x0;
    x0 += x1; x1 = rotl32(x1, 24); x1 ^= x0;
    x0 += ks2; x1 += ks0 + 2u;
    x0 += x1; x1 = rotl32(x1, 13); x1 ^= x0;
    x0 += x1; x1 = rotl32(x1, 15); x1 ^= x0;
    x0 += x1; x1 = rotl32(x1, 26); x1 ^= x0;
    x0 += x1; x1 = rotl32(x1,  6); x1 ^= x0;
    x0 += ks0; x1 += ks1 + 3u;
    x0 += x1; x1 = rotl32(x1, 17); x1 ^= x0;
    x0 += x1; x1 = rotl32(x1, 29); x1 ^= x0;
    x0 += x1; x1 = rotl32(x1, 16); x1 ^= x0;
    x0 += x1; x1 = rotl32(x1, 24); x1 ^= x0;
    x0 += ks1; x1 += ks2 + 4u;
    x0 += x1; x1 = rotl32(x1, 13); x1 ^= x0;
    x0 += x1; x1 = rotl32(x1, 15); x1 ^= x0;
    x0 += x1; x1 = rotl32(x1, 26); x1 ^= x0;
    x0 += x1; x1 = rotl32(x1,  6); x1 ^= x0;
    x0 += ks2; x1 += ks0 + 5u;
}

__device__ __forceinline__ int jax_keep_bit(int idx) {
    unsigned x0 = 0u, x1 = (unsigned)idx;
    threefry2x32(0u, 42u, x0, x1);
    unsigned bits = x0 ^ x1;
    unsigned fb = (bits >> 9) | 0x3F800000u;
    float u = __uint_as_float(fb) - 1.0f;
    return u < 0.9f ? 1 : 0;
}

__device__ __forceinline__ float dot4(float4 a, float4 b) {
    return a.x * b.x + a.y * b.y + a.z * b.z + a.w * b.w;
}

// ---------------- Phase 1: partial dots, contiguous spans ----------------
// 4-way kv split, XCD-co-located groups (the 4 g-blocks of one colblock have
// bids differing by 8 -> same XCD under round-robin -> q re-reads hit L2).
// Block cb owns contiguous columns [cb*span, cb*span+span): each of its 12
// row-streams advances 4KB/iter sequentially (DRAM page locality), vs
// grid-stride's 1MB jumps. NO tail code here (R7 lesson: fat tail wrecked
// register allocation of the hot loop, VGPR 64 -> serialized loads).
__global__ __launch_bounds__(256, 4) void qk_partial_kernel(
    const float4* __restrict__ qkv, float* __restrict__ partial,
    unsigned D4, unsigned ncb, unsigned span)
{
    const int tid = threadIdx.x;
    const int w   = tid >> 6;
    const int lane = tid & 63;

    unsigned g, cb;
    if ((ncb & (NXCD - 1)) == 0) {
        const unsigned xcd = blockIdx.x & (NXCD - 1);
        const unsigned idx = blockIdx.x >> 3;
        g  = idx & (NGRP - 1);
        cb = (idx >> 2) * NXCD + xcd;
    } else {
        g  = blockIdx.x & (NGRP - 1);
        cb = blockIdx.x >> 2;
    }

    const float4* __restrict__ kbase = qkv + (size_t)(NQ + g * KPG) * D4;

    float acc[NQ][KPG];
#pragma unroll
    for (int r = 0; r < NQ; ++r)
#pragma unroll
        for (int j = 0; j < KPG; ++j) acc[r][j] = 0.f;
    float nacc[NQ];
#pragma unroll
    for (int r = 0; r < NQ; ++r) nacc[r] = 0.f;

    const unsigned vbeg = cb * span;
    const unsigned vend = (vbeg + span < D4) ? (vbeg + span) : D4;

    for (unsigned v = vbeg + tid; v < vend; v += 256u) {
        float4 kv[KPG];
#pragma unroll
        for (int j = 0; j < KPG; ++j)
            kv[j] = kbase[(size_t)j * D4 + v];
        float4 qv[NQ];
#pragma unroll
        for (int r = 0; r < NQ; ++r)
            qv[r] = qkv[(size_t)r * D4 + v];

        if (g == 0) {
#pragma unroll
            for (int r = 0; r < NQ; ++r)
                nacc[r] += dot4(qv[r], qv[r]);
        }
#pragma unroll
        for (int r = 0; r < NQ; ++r)
#pragma unroll
            for (int j = 0; j < KPG; ++j)
                acc[r][j] += dot4(qv[r], kv[j]);
    }

    // wave shuffle-reduce the 40 partials, cross-wave combine via LDS
    __shared__ float lred[4][NPB];
#pragma unroll
    for (int r = 0; r < NQ; ++r) {
#pragma unroll
        for (int j = 0; j < KPG; ++j) {
            float s = acc[r][j];
#pragma unroll
            for (int off = 32; off >= 1; off >>= 1)
                s += __shfl_xor(s, off, 64);
            if (lane == 0) lred[w][r * KPG + j] = s;
        }
    }
    if (g == 0) {
#pragma unroll
        for (int r = 0; r < NQ; ++r) {
            float s = nacc[r];
#pragma unroll
            for (int off = 32; off >= 1; off >>= 1)
                s += __shfl_xor(s, off, 64);
            if (lane == 0) lred[w][32 + r] = s;
        }
    } else if (lane == 0) {
#pragma unroll
        for (int r = 0; r < NQ; ++r) lred[w][32 + r] = 0.f;
    }
    __syncthreads();
    // SLOT-MAJOR: partial[(g*40+slot)*ncb + cb] -> finalize reads each
    // slot as a contiguous ncb-float run (vectorizable, latency-parallel)
    if (tid < NPB) {
        const float s = lred[0][tid] + lred[1][tid] + lred[2][tid] + lred[3][tid];
        partial[(size_t)(g * NPB + tid) * ncb + cb] = s;
    }
}

// ---------------- Phase 2+3 fused: parallel reduce + softmax + dropout ----
// One block, 4 waves. Wave w reduces slots w*40..w*40+39; within a slot the
// 64 lanes read independent float4s (all loads in flight simultaneously),
// then 6-step shuffle reduce. No serial latency chain (R8 lesson).
__global__ __launch_bounds__(256) void finalize_kernel(
    const float* __restrict__ partial, float* __restrict__ out, int ncb)
{
    const int tid  = threadIdx.x;
    const int w    = tid >> 6;
    const int lane = tid & 63;
    const int ncb4 = ncb >> 2;  // ncb is a power of two >= 8 in practice

    __shared__ float wsum[NSLOT];
    const float4* __restrict__ p4 = (const float4*)partial;

#pragma unroll
    for (int i = 0; i < NPB; ++i) {
        const int slot = w * NPB + i;
        float s = 0.f;
        for (int idx = lane; idx < ncb4; idx += 64) {
            const float4 v = p4[(size_t)slot * ncb4 + idx];
            s += v.x + v.y + v.z + v.w;
        }
#pragma unroll
        for (int off = 32; off >= 1; off >>= 1)
            s += __shfl_xor(s, off, 64);
        if (lane == 0) wsum[slot] = s;
    }
    __syncthreads();

    if (tid < 128) {
        const int r = tid >> 4, j = tid & 15;
        const float norm = wsum[32 + r];  // g0 norm slots 32..39
        const float inv_scale = rsqrtf(norm + 1e-12f);
        const float logit =
            wsum[(j >> 2) * NPB + r * KPG + (j & 3)] * inv_scale;

        float m = logit;
        for (int off = 8; off >= 1; off >>= 1)
            m = fmaxf(m, __shfl_xor(m, off, 64));
        const float e = expf(logit - m);
        float ssum = e;
        for (int off = 8; off >= 1; off >>= 1)
            ssum += __shfl_xor(ssum, off, 64);

        out[tid] = jax_keep_bit(tid) ? (e / ssum / 0.9f) : 0.f;
    }
}

// ---------------- Launch --------------------------------------------------
extern "C" void kernel_launch(void* const* d_in, const int* in_sizes, int n_in,
                              void* d_out, int out_size, void* d_ws, size_t ws_size,
                              hipStream_t stream) {
    const float* qkv = (const float*)d_in[0];
    float* out = (float*)d_out;

    const long long total = (long long)in_sizes[0];
    const unsigned D  = (unsigned)(total / (NQ + NKV));
    const unsigned D4 = D / 4;

    float* wsf = (float*)d_ws;
    const long long cap_floats = (long long)(ws_size / 4);

    unsigned ncb = 256;  // 256 colblocks x 4 groups = 1024 blocks, 1 round
    while ((long long)NSLOT * ncb > cap_floats && ncb > 8) ncb >>= 1;

    // contiguous span per colblock, multiple of 256 (thread count)
    const unsigned chunks = (D4 + 255u) / 256u;
    const unsigned span = ((chunks + ncb - 1u) / ncb) * 256u;

    float* partial = wsf;  // NSLOT * ncb floats, slot-major

    qk_partial_kernel<<<ncb * NGRP, 256, 0, stream>>>(
        (const float4*)qkv, partial, D4, ncb, span);
    finalize_kernel<<<1, 256, 0, stream>>>(partial, out, (int)ncb);
}

// Round 10
// 96.190 us; speedup vs baseline: 2.6122x; 1.1799x over previous
//
#include <hip/hip_runtime.h>
#include <cstdint>

#define NQ 8
#define NKV 16
#define NGRP 4             // kv rows split across 4 block groups
#define KPG (NKV / NGRP)   // 4 kv rows per group
#define NPB 40             // per-group partial slots: 8x4 products + 8 norms
#define NSLOT (NGRP * NPB) // 160 slots
#define NXCD 8

// ---------------- Threefry-2x32 (JAX partitionable path; verified R3) ----
__device__ __forceinline__ unsigned rotl32(unsigned x, int d) {
    return (x << d) | (x >> (32 - d));
}

__device__ __forceinline__ void threefry2x32(unsigned k0, unsigned k1,
                                             unsigned& x0, unsigned& x1) {
    const unsigned ks0 = k0, ks1 = k1, ks2 = k0 ^ k1 ^ 0x1BD11BDAu;
    x0 += ks0; x1 += ks1;
    x0 += x1; x1 = rotl32(x1, 13); x1 ^= x0;
    x0 += x1; x1 = rotl32(x1, 15); x1 ^= x0;
    x0 += x1; x1 = rotl32(x1, 26); x1 ^= x0;
    x0 += x1; x1 = rotl32(x1,  6); x1 ^= x0;
    x0 += ks1; x1 += ks2 + 1u;
    x0 += x1; x1 = rotl32(x1, 17); x1 ^= x0;
    x0 += x1; x1 = rotl32(x1, 29); x1 ^= x0;
    x0 += x1; x1 = rotl32(x1, 16); x1 ^= x0;
    x0 += x1; x1 = rotl32(x1, 24); x1 ^= x0;
    x0 += ks2; x1 += ks0 + 2u;
    x0 += x1; x1 = rotl32(x1, 13); x1 ^= x0;
    x0 += x1; x1 = rotl32(x1, 15); x1 ^= x0;
    x0 += x1; x1 = rotl32(x1, 26); x1 ^= x0;
    x0 += x1; x1 = rotl32(x1,  6); x1 ^= x0;
    x0 += ks0; x1 += ks1 + 3u;
    x0 += x1; x1 = rotl32(x1, 17); x1 ^= x0;
    x0 += x1; x1 = rotl32(x1, 29); x1 ^= x0;
    x0 += x1; x1 = rotl32(x1, 16); x1 ^= x0;
    x0 += x1; x1 = rotl32(x1, 24); x1 ^= x0;
    x0 += ks1; x1 += ks2 + 4u;
    x0 += x1; x1 = rotl32(x1, 13); x1 ^= x0;
    x0 += x1; x1 = rotl32(x1, 15); x1 ^= x0;
    x0 += x1; x1 = rotl32(x1, 26); x1 ^= x0;
    x0 += x1; x1 = rotl32(x1,  6); x1 ^= x0;
    x0 += ks2; x1 += ks0 + 5u;
}

__device__ __forceinline__ int jax_keep_bit(int idx) {
    unsigned x0 = 0u, x1 = (unsigned)idx;
    threefry2x32(0u, 42u, x0, x1);
    unsigned bits = x0 ^ x1;
    unsigned fb = (bits >> 9) | 0x3F800000u;
    float u = __uint_as_float(fb) - 1.0f;
    return u < 0.9f ? 1 : 0;
}

__device__ __forceinline__ float dot4(float4 a, float4 b) {
    return a.x * b.x + a.y * b.y + a.z * b.z + a.w * b.w;
}

// ---------------- Phase 1: partial dots (R6-proven grid-stride) ----------
// 4-way kv split, XCD-co-located groups (the 4 g-blocks of one colblock have
// bids differing by 8 -> same XCD under round-robin -> q re-reads hit L2).
// Hot loop IDENTICAL to R6 (91.4us pedigree). Only the epilogue write is
// slot-major so finalize can read each slot as one coalesced float4 run.
__global__ __launch_bounds__(256, 4) void qk_partial_kernel(
    const float4* __restrict__ qkv, float* __restrict__ partial,
    unsigned D4, unsigned ncb)
{
    const int tid = threadIdx.x;
    const int w   = tid >> 6;
    const int lane = tid & 63;

    unsigned g, cb;
    if ((ncb & (NXCD - 1)) == 0) {
        const unsigned xcd = blockIdx.x & (NXCD - 1);
        const unsigned idx = blockIdx.x >> 3;
        g  = idx & (NGRP - 1);
        cb = (idx >> 2) * NXCD + xcd;
    } else {
        g  = blockIdx.x & (NGRP - 1);
        cb = blockIdx.x >> 2;
    }

    const float4* __restrict__ kbase = qkv + (size_t)(NQ + g * KPG) * D4;

    float acc[NQ][KPG];
#pragma unroll
    for (int r = 0; r < NQ; ++r)
#pragma unroll
        for (int j = 0; j < KPG; ++j) acc[r][j] = 0.f;
    float nacc[NQ];
#pragma unroll
    for (int r = 0; r < NQ; ++r) nacc[r] = 0.f;

    const unsigned stride = ncb * 256u;

    for (unsigned v = cb * 256u + tid; v < D4; v += stride) {
        float4 kv[KPG];
#pragma unroll
        for (int j = 0; j < KPG; ++j)
            kv[j] = kbase[(size_t)j * D4 + v];
        float4 qv[NQ];
#pragma unroll
        for (int r = 0; r < NQ; ++r)
            qv[r] = qkv[(size_t)r * D4 + v];

        if (g == 0) {
#pragma unroll
            for (int r = 0; r < NQ; ++r)
                nacc[r] += dot4(qv[r], qv[r]);
        }
#pragma unroll
        for (int r = 0; r < NQ; ++r)
#pragma unroll
            for (int j = 0; j < KPG; ++j)
                acc[r][j] += dot4(qv[r], kv[j]);
    }

    // wave shuffle-reduce the 40 partials, cross-wave combine via LDS
    __shared__ float lred[4][NPB];
#pragma unroll
    for (int r = 0; r < NQ; ++r) {
#pragma unroll
        for (int j = 0; j < KPG; ++j) {
            float s = acc[r][j];
#pragma unroll
            for (int off = 32; off >= 1; off >>= 1)
                s += __shfl_xor(s, off, 64);
            if (lane == 0) lred[w][r * KPG + j] = s;
        }
    }
    if (g == 0) {
#pragma unroll
        for (int r = 0; r < NQ; ++r) {
            float s = nacc[r];
#pragma unroll
            for (int off = 32; off >= 1; off >>= 1)
                s += __shfl_xor(s, off, 64);
            if (lane == 0) lred[w][32 + r] = s;
        }
    } else if (lane == 0) {
#pragma unroll
        for (int r = 0; r < NQ; ++r) lred[w][32 + r] = 0.f;
    }
    __syncthreads();
    // SLOT-MAJOR: partial[(g*40+slot)*ncb + cb]
    if (tid < NPB) {
        const float s = lred[0][tid] + lred[1][tid] + lred[2][tid] + lred[3][tid];
        partial[(size_t)(g * NPB + tid) * ncb + cb] = s;
    }
}

// ---------------- Phase 2+3 fused: latency-parallel reduce + softmax -----
// 1 block x 1024 threads (16 waves). Wave w owns 10 slots; with ncb=256
// each lane reads exactly one float4 per slot. All 10 loads are issued
// before any reduction (independent -> one latency exposure), then 10
// shuffle-reduces. No serial latency chain (R8/R9 lesson).
__global__ __launch_bounds__(1024) void finalize_kernel(
    const float* __restrict__ partial, float* __restrict__ out, int ncb)
{
    const int tid  = threadIdx.x;
    const int w    = tid >> 6;    // 0..15
    const int lane = tid & 63;
    const int ncb4 = ncb >> 2;    // ncb is a power of two (>=8)

    __shared__ float wsum[NSLOT];
    const float4* __restrict__ p4 = (const float4*)partial;

    float psum[10];
#pragma unroll
    for (int i = 0; i < 10; ++i) {          // 160 = 16 waves x 10 slots
        const int slot = w * 10 + i;
        float s = 0.f;
        for (int idx = lane; idx < ncb4; idx += 64) {
            const float4 v = p4[(size_t)slot * ncb4 + idx];
            s += v.x + v.y + v.z + v.w;
        }
        psum[i] = s;
    }
#pragma unroll
    for (int i = 0; i < 10; ++i) {
        float s = psum[i];
#pragma unroll
        for (int off = 32; off >= 1; off >>= 1)
            s += __shfl_xor(s, off, 64);
        if (lane == 0) wsum[w * 10 + i] = s;
    }
    __syncthreads();

    if (tid < 128) {
        const int r = tid >> 4, j = tid & 15;
        const float norm = wsum[32 + r];  // g0 norm slots 32..39
        const float inv_scale = rsqrtf(norm + 1e-12f);
        const float logit =
            wsum[(j >> 2) * NPB + r * KPG + (j & 3)] * inv_scale;

        float m = logit;
        for (int off = 8; off >= 1; off >>= 1)
            m = fmaxf(m, __shfl_xor(m, off, 64));
        const float e = expf(logit - m);
        float ssum = e;
        for (int off = 8; off >= 1; off >>= 1)
            ssum += __shfl_xor(ssum, off, 64);

        out[tid] = jax_keep_bit(tid) ? (e / ssum / 0.9f) : 0.f;
    }
}

// ---------------- Launch --------------------------------------------------
extern "C" void kernel_launch(void* const* d_in, const int* in_sizes, int n_in,
                              void* d_out, int out_size, void* d_ws, size_t ws_size,
                              hipStream_t stream) {
    const float* qkv = (const float*)d_in[0];
    float* out = (float*)d_out;

    const long long total = (long long)in_sizes[0];
    const unsigned D  = (unsigned)(total / (NQ + NKV));
    const unsigned D4 = D / 4;

    float* wsf = (float*)d_ws;
    const long long cap_floats = (long long)(ws_size / 4);

    unsigned ncb = 256;  // 256 colblocks x 4 groups = 1024 blocks, 1 round
    while ((long long)NSLOT * ncb > cap_floats && ncb > 8) ncb >>= 1;

    float* partial = wsf;  // NSLOT * ncb floats, slot-major

    qk_partial_kernel<<<ncb * NGRP, 256, 0, stream>>>(
        (const float4*)qkv, partial, D4, ncb);
    finalize_kernel<<<1, 1024, 0, stream>>>(partial, out, (int)ncb);
}

// Round 12
// 81.389 us; speedup vs baseline: 3.0873x; 1.1819x over previous
//
#include <hip/hip_runtime.h>
#include <cstdint>

#define NQ 8
#define NKV 16
#define NGRP 4            // kv rows split across 4 block groups
#define KPG (NKV / NGRP)  // 4 kv rows per group
#define NPB 40            // per-block partials: 8x4 products + 8 norms (g0)
#define NSUM 136          // final: 128 qk + 8 norms
#define NXCD 8

typedef float floatx4 __attribute__((ext_vector_type(4)));  // native clang
                                                            // vector: valid
                                                            // for nontemporal

// ---------------- Threefry-2x32 (JAX partitionable path; verified R3) ----
__device__ __forceinline__ unsigned rotl32(unsigned x, int d) {
    return (x << d) | (x >> (32 - d));
}

__device__ __forceinline__ void threefry2x32(unsigned k0, unsigned k1,
                                             unsigned& x0, unsigned& x1) {
    const unsigned ks0 = k0, ks1 = k1, ks2 = k0 ^ k1 ^ 0x1BD11BDAu;
    x0 += ks0; x1 += ks1;
    x0 += x1; x1 = rotl32(x1, 13); x1 ^= x0;
    x0 += x1; x1 = rotl32(x1, 15); x1 ^= x0;
    x0 += x1; x1 = rotl32(x1, 26); x1 ^= x0;
    x0 += x1; x1 = rotl32(x1,  6); x1 ^= x0;
    x0 += ks1; x1 += ks2 + 1u;
    x0 += x1; x1 = rotl32(x1, 17); x1 ^= x0;
    x0 += x1; x1 = rotl32(x1, 29); x1 ^= x0;
    x0 += x1; x1 = rotl32(x1, 16); x1 ^= x0;
    x0 += x1; x1 = rotl32(x1, 24); x1 ^= x0;
    x0 += ks2; x1 += ks0 + 2u;
    x0 += x1; x1 = rotl32(x1, 13); x1 ^= x0;
    x0 += x1; x1 = rotl32(x1, 15); x1 ^= x0;
    x0 += x1; x1 = rotl32(x1, 26); x1 ^= x0;
    x0 += x1; x1 = rotl32(x1,  6); x1 ^= x0;
    x0 += ks0; x1 += ks1 + 3u;
    x0 += x1; x1 = rotl32(x1, 17); x1 ^= x0;
    x0 += x1; x1 = rotl32(x1, 29); x1 ^= x0;
    x0 += x1; x1 = rotl32(x1, 16); x1 ^= x0;
    x0 += x1; x1 = rotl32(x1, 24); x1 ^= x0;
    x0 += ks1; x1 += ks2 + 4u;
    x0 += x1; x1 = rotl32(x1, 13); x1 ^= x0;
    x0 += x1; x1 = rotl32(x1, 15); x1 ^= x0;
    x0 += x1; x1 = rotl32(x1, 26); x1 ^= x0;
    x0 += x1; x1 = rotl32(x1,  6); x1 ^= x0;
    x0 += ks2; x1 += ks0 + 5u;
}

__device__ __forceinline__ int jax_keep_bit(int idx) {
    unsigned x0 = 0u, x1 = (unsigned)idx;
    threefry2x32(0u, 42u, x0, x1);
    unsigned bits = x0 ^ x1;
    unsigned fb = (bits >> 9) | 0x3F800000u;
    float u = __uint_as_float(fb) - 1.0f;
    return u < 0.9f ? 1 : 0;
}

__device__ __forceinline__ float dot4(float4 a, float4 b) {
    return a.x * b.x + a.y * b.y + a.z * b.z + a.w * b.w;
}

__device__ __forceinline__ float dot4v(float4 a, floatx4 b) {
    return a.x * b.x + a.y * b.y + a.z * b.z + a.w * b.w;
}

// ---------------- Phase 1: partial dots (R6 structure + nt kv loads) -----
// 4-way kv split, XCD-co-located groups (the 4 g-blocks of one colblock have
// bids differing by 8 -> same XCD under round-robin -> q re-reads hit L2).
// vs R6: kv rows loaded NONTEMPORAL (zero reuse, pure stream) so they stop
// evicting q lines from L2 / input lines from L3 (R7 profile: L3 retains
// ~half the input across replays -> cache efficiency is the margin).
__global__ __launch_bounds__(256, 4) void qk_partial_kernel(
    const float4* __restrict__ qkv, float* __restrict__ partial,
    unsigned D4, unsigned ncb)
{
    const int tid = threadIdx.x;
    const int w   = tid >> 6;
    const int lane = tid & 63;

    unsigned g, cb;
    if ((ncb & (NXCD - 1)) == 0) {
        const unsigned xcd = blockIdx.x & (NXCD - 1);
        const unsigned idx = blockIdx.x >> 3;
        g  = idx & (NGRP - 1);
        cb = (idx >> 2) * NXCD + xcd;
    } else {
        g  = blockIdx.x & (NGRP - 1);
        cb = blockIdx.x >> 2;
    }

    const floatx4* __restrict__ kbase =
        (const floatx4*)(qkv + (size_t)(NQ + g * KPG) * D4);

    float acc[NQ][KPG];
#pragma unroll
    for (int r = 0; r < NQ; ++r)
#pragma unroll
        for (int j = 0; j < KPG; ++j) acc[r][j] = 0.f;
    float nacc[NQ];
#pragma unroll
    for (int r = 0; r < NQ; ++r) nacc[r] = 0.f;

    const unsigned stride = ncb * 256u;

    for (unsigned v = cb * 256u + tid; v < D4; v += stride) {
        floatx4 kv[KPG];
#pragma unroll
        for (int j = 0; j < KPG; ++j)
            kv[j] = __builtin_nontemporal_load(&kbase[(size_t)j * D4 + v]);
        float4 qv[NQ];
#pragma unroll
        for (int r = 0; r < NQ; ++r)
            qv[r] = qkv[(size_t)r * D4 + v];

        if (g == 0) {
#pragma unroll
            for (int r = 0; r < NQ; ++r)
                nacc[r] += dot4(qv[r], qv[r]);
        }
#pragma unroll
        for (int r = 0; r < NQ; ++r)
#pragma unroll
            for (int j = 0; j < KPG; ++j)
                acc[r][j] += dot4v(qv[r], kv[j]);
    }

    // wave shuffle-reduce the 40 partials, cross-wave combine via LDS
    __shared__ float lred[4][NPB];
#pragma unroll
    for (int r = 0; r < NQ; ++r) {
#pragma unroll
        for (int j = 0; j < KPG; ++j) {
            float s = acc[r][j];
#pragma unroll
            for (int off = 32; off >= 1; off >>= 1)
                s += __shfl_xor(s, off, 64);
            if (lane == 0) lred[w][r * KPG + j] = s;
        }
    }
    if (g == 0) {
#pragma unroll
        for (int r = 0; r < NQ; ++r) {
            float s = nacc[r];
#pragma unroll
            for (int off = 32; off >= 1; off >>= 1)
                s += __shfl_xor(s, off, 64);
            if (lane == 0) lred[w][32 + r] = s;
        }
    } else if (lane == 0) {
#pragma unroll
        for (int r = 0; r < NQ; ++r) lred[w][32 + r] = 0.f;
    }
    __syncthreads();
    // cb-major contiguous 160B block per (cb,g) -- R6-proven layout
    if (tid < NPB) {
        const float s = lred[0][tid] + lred[1][tid] + lred[2][tid] + lred[3][tid];
        partial[(size_t)(cb * NGRP + g) * NPB + tid] = s;
    }
}

// ---------------- Phase 2: reduce partials across colblocks ---------------
__global__ __launch_bounds__(256) void reduce_kernel(
    const float* __restrict__ partial, float* __restrict__ sums, int ncb)
{
    const int s = blockIdx.x;  // 0..135
    int g, slot;
    if (s < 128) {
        const int r = s >> 4, j = s & 15;
        g = j >> 2; slot = r * KPG + (j & 3);
    } else {
        g = 0; slot = 32 + (s - 128);
    }

    float acc = 0.f;
    for (int cb = threadIdx.x; cb < ncb; cb += 256)
        acc += partial[(size_t)(cb * NGRP + g) * NPB + slot];

    float vsum = acc;
    for (int off = 32; off >= 1; off >>= 1)
        vsum += __shfl_xor(vsum, off, 64);

    __shared__ float red[4];
    const int w = threadIdx.x >> 6, lane = threadIdx.x & 63;
    if (lane == 0) red[w] = vsum;
    __syncthreads();
    if (threadIdx.x == 0) sums[s] = red[0] + red[1] + red[2] + red[3];
}

// ---------------- Phase 3: scale, softmax, dropout ------------------------
__global__ __launch_bounds__(128) void finalize_kernel(
    const float* __restrict__ sums, float* __restrict__ out)
{
    const int idx = threadIdx.x;  // 0..127
    const int r = idx >> 4;

    const float norm = sums[128 + r];
    const float inv_scale = rsqrtf(norm + 1e-12f);
    const float logit = sums[idx] * inv_scale;

    float m = logit;
    for (int off = 8; off >= 1; off >>= 1)
        m = fmaxf(m, __shfl_xor(m, off, 64));
    const float e = expf(logit - m);
    float ssum = e;
    for (int off = 8; off >= 1; off >>= 1)
        ssum += __shfl_xor(ssum, off, 64);
    const float sm = e / ssum;

    out[idx] = jax_keep_bit(idx) ? (sm / 0.9f) : 0.f;
}

// ---------------- Launch --------------------------------------------------
extern "C" void kernel_launch(void* const* d_in, const int* in_sizes, int n_in,
                              void* d_out, int out_size, void* d_ws, size_t ws_size,
                              hipStream_t stream) {
    const float* qkv = (const float*)d_in[0];
    float* out = (float*)d_out;

    const long long total = (long long)in_sizes[0];
    const unsigned D  = (unsigned)(total / (NQ + NKV));
    const unsigned D4 = D / 4;

    float* wsf = (float*)d_ws;
    const long long cap_floats = (long long)(ws_size / 4);

    unsigned ncb = 256;  // 256 colblocks x 4 groups = 1024 blocks, 1 round
    long long need = (long long)ncb * NGRP * NPB + NSUM;
    while (need > cap_floats && ncb > 1) {
        ncb >>= 1;
        need = (long long)ncb * NGRP * NPB + NSUM;
    }

    float* partial = wsf;
    float* sums    = wsf + (long long)ncb * NGRP * NPB;

    qk_partial_kernel<<<ncb * NGRP, 256, 0, stream>>>(
        (const float4*)qkv, partial, D4, ncb);
    reduce_kernel<<<NSUM, 256, 0, stream>>>(partial, sums, (int)ncb);
    finalize_kernel<<<1, 128, 0, stream>>>(sums, out);
}